// Round 1
// 1081.420 us; speedup vs baseline: 1.0014x; 1.0014x over previous
//
#include <hip/hip_runtime.h>

// R8ConvF fused: out[b,o,d,h,w] = sum_{c,k} w[o,c,k] * x[b,c,h+(k-1)dy_d, w+(k-1)dx_d]
// One kernel: stage halo'd x tile in LDS as bf16, layout [position][c] (XOR-swizzled)
// so MFMA B-fragments are single ds_read_b128. Center tap (k=1) computed once,
// shared across all 8 dirs; shift pairs (d, d+4) share their +/- shifted fragments.
// B=16 C=128 O=128 H=W=112 K=3.

#define Bn 16
#define Cn 128
#define On 128
#define Hn 112
#define Wn 112
#define HW 12544        // 112*112

#define NR 66           // LDS wfull-columns per h-row (64-chunk + 2 halo)
#define LROW 128        // u16 per LDS row (the c dimension)

typedef short short8 __attribute__((ext_vector_type(8)));
typedef float floatx4 __attribute__((ext_vector_type(4)));

__device__ __forceinline__ unsigned short f2bf(float f) {
    unsigned u = __float_as_uint(f);
    u += 0x7FFFu + ((u >> 16) & 1u);   // round-to-nearest-even
    return (unsigned short)(u >> 16);
}

// ---- prep: weight fp32 [O][C][3] -> wb bf16 [3][O][C] ----------------------
__global__ __launch_bounds__(256) void prep_w(const float* __restrict__ w,
                                              unsigned short* __restrict__ wb) {
    int i = blockIdx.x * 256 + threadIdx.x;     // exactly 3*128*128 = 49152
    int k = i >> 14;
    int r = i & 16383;
    int o = r >> 7, c = r & 127;
    wb[i] = f2bf(w[(o * Cn + c) * 3 + k]);
}

// ---- fused conv: grid (112, B), block 256 = 4 waves ------------------------
// blockIdx.x: wc = bx&1 (w-chunk: 64 cols / 48 cols), hs = bx>>1 (2-row stripe).
// Each wave owns 32 o-rows (2 M-frags of 16). LDS x tile: 4 rows x 66 wfull x 128 c
// bf16, row index r = hr*NR + wfull, swizzle c' = c ^ ((r&15)<<3). 67.6 KB -> 2 blk/CU.
__global__ __launch_bounds__(256, 2) void conv8(const float* __restrict__ x,
                                                const unsigned short* __restrict__ wb,
                                                float* __restrict__ out) {
    __shared__ unsigned short xs[4 * NR * LROW];    // 67,584 B
    const int t = threadIdx.x;
    const int wv = t >> 6, lane = t & 63;
    const int n16 = lane & 15, q = lane >> 4;
    const int bx = blockIdx.x;
    const int b = blockIdx.y;
    const int wc = bx & 1, hs = bx >> 1;
    const int h0 = hs * 2;
    const int wbase = wc * 64;
    const int NT = wc ? 3 : 4;          // 16-wide w tiles in this chunk

    // zero LDS (covers all halo: out-of-image rows/cols stay 0)
    {
        int4* p = (int4*)xs;
        for (int i = t; i < (4 * NR * LROW) / 8; i += 256)
            p[i] = make_int4(0, 0, 0, 0);
    }

    // A fragments: lane holds W_k[o = og + oi*16 + n16][c = kc*32 + q*8 + j]
    short8 af[3][2][4];
    const int og = wv * 32;
    #pragma unroll
    for (int k = 0; k < 3; ++k)
        #pragma unroll
        for (int oi = 0; oi < 2; ++oi) {
            int o = og + oi * 16 + n16;
            #pragma unroll
            for (int kc = 0; kc < 4; ++kc)
                af[k][oi][kc] = *(const short8*)(wb + ((k * On + o) * Cn + kc * 32 + q * 8));
        }
    __syncthreads();    // zero-fill complete

    // stage x -> LDS bf16, transposed to [position][c], swizzled.
    // jobs: hr(4) x c(128) x slot(18); slot covers w = wbase-4+slot*4 .. +3 (float4).
    for (int i = t; i < 4 * 128 * 18; i += 256) {
        int slot = i % 18;
        int rem = i / 18;           // < 512
        int c = rem & 127, hr = rem >> 7;
        int h = h0 - 1 + hr;
        if ((unsigned)h >= Hn) continue;
        int w0 = wbase - 4 + slot * 4;
        if (w0 < 0 || w0 >= Wn) continue;       // slots are fully valid or fully not
        float4 v = *(const float4*)(x + ((size_t)(b * Cn + c) * Hn + h) * Wn + w0);
        float vv[4] = {v.x, v.y, v.z, v.w};
        int wf0 = w0 - wbase + 1;
        #pragma unroll
        for (int cc = 0; cc < 4; ++cc) {
            int wf = wf0 + cc;
            if ((unsigned)wf < NR) {
                int r = hr * NR + wf;
                xs[r * LROW + (c ^ ((r & 15) << 3))] = f2bf(vv[cc]);
            }
        }
    }
    __syncthreads();

    const int DY[4] = {0, 1, 1, 1};     // dirs 0..3; dirs 4..7 are the negations
    const int DX[4] = {1, 1, 0, -1};

    for (int ht = 0; ht < 2; ++ht) {
        const int h = h0 + ht;
        for (int wt = 0; wt < NT; ++wt) {
            const int rb = (1 + ht) * NR + 1 + wt * 16 + n16;   // center position row
            // center-tap fragments + GEMM (shared by all 8 dirs)
            short8 fc[4];
            #pragma unroll
            for (int kc = 0; kc < 4; ++kc) {
                int cb = kc * 32 + q * 8;
                fc[kc] = *(const short8*)(xs + rb * LROW + (cb ^ ((rb & 15) << 3)));
            }
            floatx4 acc1[2];
            #pragma unroll
            for (int oi = 0; oi < 2; ++oi) {
                floatx4 a = {0.f, 0.f, 0.f, 0.f};
                #pragma unroll
                for (int kc = 0; kc < 4; ++kc)
                    a = __builtin_amdgcn_mfma_f32_16x16x32_bf16(af[1][oi][kc], fc[kc], a, 0, 0, 0);
                acc1[oi] = a;
            }
            size_t obase = ((size_t)b * On * 8) * HW + (size_t)h * Wn + wbase + wt * 16 + n16;
            #pragma unroll
            for (int pr = 0; pr < 4; ++pr) {    // shift pair: d = pr, d+4 = pr+4
                int dy = DY[pr], dx = DX[pr];
                int rm = rb - dy * NR - dx;     // position p - delta
                int rp = rb + dy * NR + dx;     // position p + delta
                short8 fm[4], fp[4];
                #pragma unroll
                for (int kc = 0; kc < 4; ++kc) {
                    int cb = kc * 32 + q * 8;
                    fm[kc] = *(const short8*)(xs + rm * LROW + (cb ^ ((rm & 15) << 3)));
                    fp[kc] = *(const short8*)(xs + rp * LROW + (cb ^ ((rp & 15) << 3)));
                }
                #pragma unroll
                for (int oi = 0; oi < 2; ++oi) {
                    floatx4 ad = {0.f, 0.f, 0.f, 0.f};
                    floatx4 ad4 = {0.f, 0.f, 0.f, 0.f};
                    #pragma unroll
                    for (int kc = 0; kc < 4; ++kc) {
                        ad  = __builtin_amdgcn_mfma_f32_16x16x32_bf16(af[0][oi][kc], fm[kc], ad, 0, 0, 0);
                        ad  = __builtin_amdgcn_mfma_f32_16x16x32_bf16(af[2][oi][kc], fp[kc], ad, 0, 0, 0);
                        ad4 = __builtin_amdgcn_mfma_f32_16x16x32_bf16(af[0][oi][kc], fp[kc], ad4, 0, 0, 0);
                        ad4 = __builtin_amdgcn_mfma_f32_16x16x32_bf16(af[2][oi][kc], fm[kc], ad4, 0, 0, 0);
                    }
                    // D layout: row(o) = q*4 + rr, col(p) = n16
                    #pragma unroll
                    for (int rr = 0; rr < 4; ++rr) {
                        int o = og + oi * 16 + q * 4 + rr;
                        out[obase + ((size_t)o * 8 + pr) * HW]     = ad[rr]  + acc1[oi][rr];
                        out[obase + ((size_t)o * 8 + pr + 4) * HW] = ad4[rr] + acc1[oi][rr];
                    }
                }
            }
        }
    }
}

// ---- naive fallback (only if workspace < 96 KB for weights) ----------------
__global__ __launch_bounds__(256) void k_naive(const float* __restrict__ x,
                                               const float* __restrict__ w,
                                               float* __restrict__ out) {
    const int DY[8] = {0, 1, 1, 1, 0, -1, -1, -1};
    const int DX[8] = {1, 1, 0, -1, -1, -1, 0, 1};
    size_t idx = (size_t)blockIdx.x * 256 + threadIdx.x;
    if (idx >= (size_t)Bn * On * 8 * HW) return;
    int ww = idx % Wn; size_t r = idx / Wn;
    int hh = r % Hn; r /= Hn;
    int d = r % 8; r /= 8;
    int o = r % On; int b = (int)(r / On);
    float s = 0.f;
    for (int c = 0; c < Cn; ++c)
        for (int k = 0; k < 3; ++k) {
            int h2 = hh + (k - 1) * DY[d], w2 = ww + (k - 1) * DX[d];
            if (h2 >= 0 && h2 < Hn && w2 >= 0 && w2 < Wn)
                s += w[(o * Cn + c) * 3 + k] * x[(size_t)(b * Cn + c) * HW + h2 * Wn + w2];
        }
    out[idx] = s;
}

extern "C" void kernel_launch(void* const* d_in, const int* in_sizes, int n_in,
                              void* d_out, int out_size, void* d_ws, size_t ws_size,
                              hipStream_t stream) {
    const float* x = (const float*)d_in[0];
    const float* w = (const float*)d_in[1];
    float* out = (float*)d_out;

    if (ws_size < 98304) {      // cannot hold bf16 weights: slow-but-correct path
        size_t total = (size_t)Bn * On * 8 * HW;
        k_naive<<<dim3((unsigned)((total + 255) / 256)), 256, 0, stream>>>(x, w, out);
        return;
    }

    unsigned short* wb = (unsigned short*)d_ws;     // 96 KB bf16 weights [3][O][C]
    prep_w<<<192, 256, 0, stream>>>(w, wb);
    conv8<<<dim3(112, Bn), 256, 0, stream>>>(x, wb, out);
}